// Round 2
// 326.569 us; speedup vs baseline: 1.3838x; 1.3838x over previous
//
#include <hip/hip_runtime.h>

#define S_LEN 4096
#define DIM 64
#define NHEAD 64        // B*H = 4*16
#define LDK 68          // padded leading dim for pass1 LDS tiles
#define PHEAD 4160      // 65*64 floats per head: rows e=0..63 are KV^T, row 64 = Ksum

__device__ __forceinline__ float elu1(float x) {
    // elu(x)+1 : x>0 -> x+1 ; x<=0 -> exp(x)
    return x > 0.0f ? x + 1.0f : __expf(x);
}

// ---------------- pass 1: partial KV (64x64, stored e-major) + Ksum per (head, chunk) ----
// nchunk = 1<<sh chunks per head (runtime: 16 if workspace allows, else 8).
__global__ __launch_bounds__(256) void pass1_kv(
    const float* __restrict__ K, const float* __restrict__ V,
    const float* __restrict__ mask, float* __restrict__ partials, int sh)
{
    const int head  = blockIdx.x >> sh;
    const int chunk = blockIdx.x & ((1 << sh) - 1);
    const int ntile = (S_LEN / 64) >> sh;
    const int t  = threadIdx.x;
    const int tx = t & 15;        // e-group
    const int ty = t >> 4;        // d-group
    const int e0 = tx * 4;
    const int d0 = ty * 4;

    __shared__ float kf[64 * LDK];
    __shared__ float vf[64 * LDK];

    float acc[4][4] = {{0.f,0.f,0.f,0.f},{0.f,0.f,0.f,0.f},{0.f,0.f,0.f,0.f},{0.f,0.f,0.f,0.f}};
    float ks[4] = {0.f, 0.f, 0.f, 0.f};

    const long hbase = (long)head * S_LEN * DIM;

    for (int tile = 0; tile < ntile; ++tile) {
        const int sbase = (chunk * ntile + tile) * 64;
        __syncthreads();   // protect LDS reads of previous tile
        // stage 64 rows x 64 cols of K (featurized+masked) and V: 1024 float4, 4 per thread
        #pragma unroll
        for (int i = 0; i < 4; ++i) {
            const int v4  = i * 256 + t;
            const int row = v4 >> 4;
            const int col = (v4 & 15) * 4;
            const float4 kq = *(const float4*)(K + hbase + (long)(sbase + row) * DIM + col);
            const float4 vq = *(const float4*)(V + hbase + (long)(sbase + row) * DIM + col);
            const float m = mask[head * S_LEN + sbase + row];
            float4 ko;
            ko.x = elu1(kq.x) * m; ko.y = elu1(kq.y) * m;
            ko.z = elu1(kq.z) * m; ko.w = elu1(kq.w) * m;
            *(float4*)&kf[row * LDK + col] = ko;
            *(float4*)&vf[row * LDK + col] = vq;
        }
        __syncthreads();
        #pragma unroll 4
        for (int s = 0; s < 64; ++s) {
            const float4 kk = *(const float4*)&kf[s * LDK + d0];
            const float4 vv = *(const float4*)&vf[s * LDK + e0];
            acc[0][0] += kk.x * vv.x; acc[0][1] += kk.x * vv.y; acc[0][2] += kk.x * vv.z; acc[0][3] += kk.x * vv.w;
            acc[1][0] += kk.y * vv.x; acc[1][1] += kk.y * vv.y; acc[1][2] += kk.y * vv.z; acc[1][3] += kk.y * vv.w;
            acc[2][0] += kk.z * vv.x; acc[2][1] += kk.z * vv.y; acc[2][2] += kk.z * vv.z; acc[2][3] += kk.z * vv.w;
            acc[3][0] += kk.w * vv.x; acc[3][1] += kk.w * vv.y; acc[3][2] += kk.w * vv.z; acc[3][3] += kk.w * vv.w;
            // unconditional (identical across tx within a ty-group) — no exec-mask churn
            ks[0] += kk.x; ks[1] += kk.y; ks[2] += kk.z; ks[3] += kk.w;
        }
    }

    // store partial, transposed layout: P[e][d]  (e-major)
    float* P = partials + (long)((head << sh) + chunk) * PHEAD;
    #pragma unroll
    for (int ei = 0; ei < 4; ++ei) {
        float4 w = make_float4(acc[0][ei], acc[1][ei], acc[2][ei], acc[3][ei]);
        *(float4*)(P + (e0 + ei) * 64 + d0) = w;
    }
    if (tx == 0) {
        *(float4*)(P + 64 * 64 + d0) = make_float4(ks[0], ks[1], ks[2], ks[3]);
    }
}

// ---------------- reduce: sum nchunk partials -> final KV^T (+Ksum) per head ----------------
// 8 blocks per head so the grid actually covers the machine.
__global__ __launch_bounds__(256) void reduce_kv(
    const float* __restrict__ partials, float* __restrict__ kvf, int nchunk)
{
    const int head  = blockIdx.x >> 3;
    const int slice = blockIdx.x & 7;
    const int lo = slice * (PHEAD / 8);
    const int hi = lo + (PHEAD / 8);
    for (int idx = lo + threadIdx.x; idx < hi; idx += 256) {
        float s = 0.f;
        for (int c = 0; c < nchunk; ++c)
            s += partials[((long)head * nchunk + c) * PHEAD + idx];
        kvf[(long)head * PHEAD + idx] = s;
    }
}

// ---------------- pass 2: out = (Qf @ KV) / (Qf . Ksum) ----------------
// Each wave owns a private 64-row tile: lane = row, whole Qf row in 64 VGPRs.
// KV addresses depend only on blockIdx + loop counters -> provably uniform ->
// scalar s_load pipe; inner loop is pure v_fmac with one SGPR operand.
// Wave-private LDS slice (16 KiB each, 64 KiB total): XOR group-swizzle
// (g ^= row&15 on float4 groups) makes all four phases bank-conflict-free
// without padding. LDS ops of one wave execute in order -> wave_barrier
// (compiler fence) suffices; no __syncthreads in this kernel.
__global__ __launch_bounds__(256) void pass2_out(
    const float* __restrict__ Q, const float* __restrict__ kvf,
    float* __restrict__ out)
{
    const int head = blockIdx.x >> 4;     // 16 tiles of 256 rows per head
    const int tile = blockIdx.x & 15;
    const int t    = threadIdx.x;
    const int lane = t & 63;
    const int wave = t >> 6;
    const int lx   = lane & 15;

    __shared__ float sm[4][64 * 64];      // per-wave private slice, 65536 B total
    float* sl = sm[wave];

    const long hbase = (long)head * S_LEN * DIM;
    const int  rbase = tile * 256 + wave * 64;   // this wave's first row

    // (a) stage this wave's 64x64 Q subtile, coalesced (1 KiB/instr), elu+1 applied
    #pragma unroll
    for (int i = 0; i < 16; ++i) {
        const int row = i * 4 + (lane >> 4);
        const int g   = lane & 15;
        const float4 qv = *(const float4*)(Q + hbase + (long)(rbase + row) * DIM + g * 4);
        float4 qo;
        qo.x = elu1(qv.x); qo.y = elu1(qv.y); qo.z = elu1(qv.z); qo.w = elu1(qv.w);
        *(float4*)&sl[row * 64 + ((g ^ (row & 15)) * 4)] = qo;
    }
    __builtin_amdgcn_wave_barrier();

    // (b) each lane pulls its entire row into registers (swizzled -> conflict-free)
    float q[64];
    #pragma unroll
    for (int g = 0; g < 16; ++g) {
        const float4 v = *(const float4*)&sl[lane * 64 + ((g ^ lx) * 4)];
        q[g * 4 + 0] = v.x; q[g * 4 + 1] = v.y; q[g * 4 + 2] = v.z; q[g * 4 + 3] = v.w;
    }
    __builtin_amdgcn_wave_barrier();

    const float* __restrict__ kvt = kvf + (long)head * PHEAD;

    // denominator: Qf . Ksum — uniform address -> scalar loads
    float denom = 0.f;
    #pragma unroll
    for (int d = 0; d < 64; ++d) denom += q[d] * kvt[64 * 64 + d];
    const float rz = 1.0f / denom;

    // (c) all 64 output cols, 4 at a time; kvt rows are block-uniform -> s_load
    // bursts (64 floats per er sub-loop keeps SGPR pressure sane).
    #pragma unroll 1
    for (int eg = 0; eg < 16; ++eg) {
        const float* __restrict__ r = kvt + eg * 256;   // rows e = 4*eg .. 4*eg+3
        float a[4];
        #pragma unroll
        for (int er = 0; er < 4; ++er) {
            float acc = 0.f;
            #pragma unroll
            for (int d = 0; d < 64; ++d) acc += q[d] * r[er * 64 + d];
            a[er] = acc;
        }
        *(float4*)&sl[lane * 64 + ((eg ^ lx) * 4)] =
            make_float4(a[0] * rz, a[1] * rz, a[2] * rz, a[3] * rz);
    }
    __builtin_amdgcn_wave_barrier();

    // (d) readback (unswizzle) + fully coalesced 1 KiB stores
    #pragma unroll
    for (int i = 0; i < 16; ++i) {
        const int row = i * 4 + (lane >> 4);
        const int g   = lane & 15;
        const float4 o = *(const float4*)&sl[row * 64 + ((g ^ (row & 15)) * 4)];
        *(float4*)(out + hbase + (long)(rbase + row) * DIM + g * 4) = o;
    }
}

extern "C" void kernel_launch(void* const* d_in, const int* in_sizes, int n_in,
                              void* d_out, int out_size, void* d_ws, size_t ws_size,
                              hipStream_t stream) {
    const float* Q    = (const float*)d_in[0];
    const float* K    = (const float*)d_in[1];
    const float* V    = (const float*)d_in[2];
    const float* mask = (const float*)d_in[3];
    float* out = (float*)d_out;

    // NCHUNK=16 needs ~18.1 MB workspace; fall back to the proven 8-chunk (9.6 MB) layout
    const size_t need16 = ((size_t)NHEAD * 16 * PHEAD + (size_t)NHEAD * PHEAD) * sizeof(float);
    const int sh = (ws_size >= need16) ? 4 : 3;
    const int nchunk = 1 << sh;

    float* partials = (float*)d_ws;
    float* kvf = partials + (size_t)NHEAD * nchunk * PHEAD;

    pass1_kv<<<NHEAD * nchunk, 256, 0, stream>>>(K, V, mask, partials, sh);
    reduce_kv<<<NHEAD * 8, 256, 0, stream>>>(partials, kvf, nchunk);
    pass2_out<<<NHEAD * 16, 256, 0, stream>>>(Q, kvf, out);
}

// Round 3
// 315.364 us; speedup vs baseline: 1.4329x; 1.0355x over previous
//
#include <hip/hip_runtime.h>

#define S_LEN 4096
#define DIM 64
#define NHEAD 64        // B*H = 4*16
#define PHEAD 4160      // 65*64 floats per head: rows e=0..63 are KV^T (e-major), row 64 = Ksum
#define LDR 68          // pass1 LDS row stride (floats)

__device__ __forceinline__ float elu1(float x) {
    // elu(x)+1 : x>0 -> x+1 ; x<=0 -> exp(x)
    return x > 0.0f ? x + 1.0f : __expf(x);
}

// ---------------- pass 1: partial KV (64x64, e-major) + Ksum per (head, block-chunk) ----
// Grid: NHEAD << sh blocks of 256. Block covers S_LEN>>sh rows; each of its 4 waves
// independently accumulates a full 64x64 KV over a quarter of those rows using 8x8
// per-lane register tiles (sync-free main loop, wave-private double-buffered staging,
// next tile's global loads issued before current tile's compute). Waves reduce via
// LDS at the end -> one partial per block.
__global__ __launch_bounds__(256, 4) void pass1_kv(
    const float* __restrict__ K, const float* __restrict__ V,
    const float* __restrict__ mask, float* __restrict__ partials, int sh)
{
    const int head = blockIdx.x >> sh;
    const int blkc = blockIdx.x & ((1 << sh) - 1);
    const int t    = threadIdx.x;
    const int lane = t & 63;
    const int wave = t >> 6;
    const int ex   = lane & 7;        // e-group: V cols e0..e0+7
    const int dy   = lane >> 3;       // d-group: K cols d0..d0+7
    const int e0   = ex * 8;
    const int d0   = dy * 8;

    const int rows_per_wave = (S_LEN >> sh) >> 2;   // sh=4 -> 64
    const int ntiles = rows_per_wave >> 3;          // 8-row tiles
    const int srow0  = (blkc * 4 + wave) * rows_per_wave;

    // wave-private double-buffered staging: [wave][buf][K/V][8*LDR] = 34816 B total
    __shared__ float sm[4][2][2][8 * LDR];

    const long hbase = (long)head * S_LEN * DIM;

    float acc[8][8];
    #pragma unroll
    for (int i = 0; i < 8; ++i)
        #pragma unroll
        for (int j = 0; j < 8; ++j) acc[i][j] = 0.f;
    float ks[8] = {0.f,0.f,0.f,0.f,0.f,0.f,0.f,0.f};

    float4 kr[2], vr[2];
    float  mr[2];
    auto load_tile = [&](int tile) {
        const int srow = srow0 + tile * 8;
        #pragma unroll
        for (int j = 0; j < 2; ++j) {
            const int v4   = j * 64 + lane;
            const int row  = v4 >> 4;           // 0..7
            const int colg = (v4 & 15) * 4;
            kr[j] = *(const float4*)(K + hbase + (long)(srow + row) * DIM + colg);
            vr[j] = *(const float4*)(V + hbase + (long)(srow + row) * DIM + colg);
            mr[j] = mask[head * S_LEN + srow + row];
        }
    };

    load_tile(0);
    for (int tile = 0; tile < ntiles; ++tile) {
        float* kf = sm[wave][tile & 1][0];
        float* vf = sm[wave][tile & 1][1];
        // featurize + write current tile to LDS (waits on its global loads)
        #pragma unroll
        for (int j = 0; j < 2; ++j) {
            const int v4   = j * 64 + lane;
            const int row  = v4 >> 4;
            const int colg = (v4 & 15) * 4;
            float4 ko;
            ko.x = elu1(kr[j].x) * mr[j]; ko.y = elu1(kr[j].y) * mr[j];
            ko.z = elu1(kr[j].z) * mr[j]; ko.w = elu1(kr[j].w) * mr[j];
            *(float4*)&kf[row * LDR + colg] = ko;
            *(float4*)&vf[row * LDR + colg] = vr[j];
        }
        // issue next tile's global loads now; they complete under compute below
        if (tile + 1 < ntiles) load_tile(tile + 1);
        __builtin_amdgcn_wave_barrier();
        #pragma unroll 2
        for (int s = 0; s < 8; ++s) {
            float kk[8], vv[8];
            *(float4*)&kk[0] = *(const float4*)&kf[s * LDR + d0];
            *(float4*)&kk[4] = *(const float4*)&kf[s * LDR + d0 + 4];
            *(float4*)&vv[0] = *(const float4*)&vf[s * LDR + e0];
            *(float4*)&vv[4] = *(const float4*)&vf[s * LDR + e0 + 4];
            #pragma unroll
            for (int ei = 0; ei < 8; ++ei)
                #pragma unroll
                for (int di = 0; di < 8; ++di)
                    acc[ei][di] += kk[di] * vv[ei];
            #pragma unroll
            for (int di = 0; di < 8; ++di) ks[di] += kk[di];
        }
        __builtin_amdgcn_wave_barrier();
    }

    // -------- in-block reduce of the 4 wave-partials via LDS --------
    __syncthreads();
    float* red = (float*)sm;   // 4160 floats (16.6 KB of the 34.8 KB pool)
    for (int w = 0; w < 4; ++w) {
        if (wave == w) {
            if (w == 0) {
                #pragma unroll
                for (int ei = 0; ei < 8; ++ei) {
                    *(float4*)&red[(e0 + ei) * 64 + d0]     = make_float4(acc[ei][0], acc[ei][1], acc[ei][2], acc[ei][3]);
                    *(float4*)&red[(e0 + ei) * 64 + d0 + 4] = make_float4(acc[ei][4], acc[ei][5], acc[ei][6], acc[ei][7]);
                }
                if (ex == 0) {
                    *(float4*)&red[4096 + d0]     = make_float4(ks[0], ks[1], ks[2], ks[3]);
                    *(float4*)&red[4096 + d0 + 4] = make_float4(ks[4], ks[5], ks[6], ks[7]);
                }
            } else {
                #pragma unroll
                for (int ei = 0; ei < 8; ++ei) {
                    float4 a = *(float4*)&red[(e0 + ei) * 64 + d0];
                    a.x += acc[ei][0]; a.y += acc[ei][1]; a.z += acc[ei][2]; a.w += acc[ei][3];
                    *(float4*)&red[(e0 + ei) * 64 + d0] = a;
                    float4 b = *(float4*)&red[(e0 + ei) * 64 + d0 + 4];
                    b.x += acc[ei][4]; b.y += acc[ei][5]; b.z += acc[ei][6]; b.w += acc[ei][7];
                    *(float4*)&red[(e0 + ei) * 64 + d0 + 4] = b;
                }
                if (ex == 0) {
                    float4 a = *(float4*)&red[4096 + d0];
                    a.x += ks[0]; a.y += ks[1]; a.z += ks[2]; a.w += ks[3];
                    *(float4*)&red[4096 + d0] = a;
                    float4 b = *(float4*)&red[4096 + d0 + 4];
                    b.x += ks[4]; b.y += ks[5]; b.z += ks[6]; b.w += ks[7];
                    *(float4*)&red[4096 + d0 + 4] = b;
                }
            }
        }
        __syncthreads();
    }
    float* P = partials + (long)((head << sh) + blkc) * PHEAD;
    for (int i = t; i < PHEAD / 4; i += 256)
        *(float4*)(P + i * 4) = *(const float4*)&red[i * 4];
}

// ---------------- reduce: sum nchunk partials -> final KV^T (+Ksum) per head ----------------
__global__ __launch_bounds__(256) void reduce_kv(
    const float* __restrict__ partials, float* __restrict__ kvf, int nchunk)
{
    const int head  = blockIdx.x >> 3;
    const int slice = blockIdx.x & 7;
    const int lo = slice * (PHEAD / 8);
    const int hi = lo + (PHEAD / 8);
    for (int idx = lo + threadIdx.x; idx < hi; idx += 256) {
        float s = 0.f;
        for (int c = 0; c < nchunk; ++c)
            s += partials[((long)head * nchunk + c) * PHEAD + idx];
        kvf[(long)head * PHEAD + idx] = s;
    }
}

// ---------------- pass 2: out = (Qf @ KV) / (Qf . Ksum) ----------------
// Lane = row, full Qf row in 64 VGPRs; KV addresses uniform -> s_load pipe.
// LDS cut to 36 KiB/block (one 64x36 rotate-swizzled slab per wave, used in
// 32-column phases for Q-stage and output-transpose) -> 4 blocks/CU = 16 waves/CU,
// double the latency-hiding occupancy of the 64 KiB version. Sync-free.
__global__ __launch_bounds__(256, 4) void pass2_out(
    const float* __restrict__ Q, const float* __restrict__ kvf,
    float* __restrict__ out)
{
    const int head = blockIdx.x >> 4;     // 16 tiles of 256 rows per head
    const int tile = blockIdx.x & 15;
    const int t    = threadIdx.x;
    const int lane = t & 63;
    const int wave = t >> 6;

    __shared__ float sm[4][64 * 36];      // 36864 B total
    float* sl = sm[wave];

    const long hbase = (long)head * S_LEN * DIM;
    const int  rbase = tile * 256 + wave * 64;   // this wave's first row

    // stage Q in two 32-col slabs (coalesced), pull per-lane rows into registers
    float q[64];
    #pragma unroll
    for (int h = 0; h < 2; ++h) {
        #pragma unroll
        for (int i = 0; i < 8; ++i) {
            const int v4  = i * 64 + lane;
            const int row = v4 >> 3;          // 0..63
            const int g   = v4 & 7;           // col-group within half
            const float4 qv = *(const float4*)(Q + hbase + (long)(rbase + row) * DIM + h * 32 + g * 4);
            float4 qo;
            qo.x = elu1(qv.x); qo.y = elu1(qv.y); qo.z = elu1(qv.z); qo.w = elu1(qv.w);
            *(float4*)&sl[row * 36 + ((g + row) & 7) * 4] = qo;
        }
        __builtin_amdgcn_wave_barrier();
        #pragma unroll
        for (int g = 0; g < 8; ++g) {
            const float4 v = *(const float4*)&sl[lane * 36 + ((g + lane) & 7) * 4];
            q[h * 32 + g * 4 + 0] = v.x; q[h * 32 + g * 4 + 1] = v.y;
            q[h * 32 + g * 4 + 2] = v.z; q[h * 32 + g * 4 + 3] = v.w;
        }
        __builtin_amdgcn_wave_barrier();
    }

    const float* __restrict__ kvt = kvf + (long)head * PHEAD;

    // denominator: Qf . Ksum — uniform address -> scalar loads
    float denom = 0.f;
    #pragma unroll
    for (int d = 0; d < 64; ++d) denom += q[d] * kvt[64 * 64 + d];
    const float rz = 1.0f / denom;

    // 64 output cols in two 32-col halves; kvt rows block-uniform -> s_load bursts
    #pragma unroll
    for (int h = 0; h < 2; ++h) {
        #pragma unroll 1
        for (int eg = 0; eg < 8; ++eg) {
            const float* __restrict__ r = kvt + (h * 8 + eg) * 256;  // rows e=4*(h*8+eg)..+3
            float a[4];
            #pragma unroll
            for (int er = 0; er < 4; ++er) {
                float s = 0.f;
                #pragma unroll
                for (int d = 0; d < 64; ++d) s += q[d] * r[er * 64 + d];
                a[er] = s;
            }
            *(float4*)&sl[lane * 36 + ((eg + lane) & 7) * 4] =
                make_float4(a[0] * rz, a[1] * rz, a[2] * rz, a[3] * rz);
        }
        __builtin_amdgcn_wave_barrier();
        // transpose-readback + fully coalesced stores of this 32-col half
        #pragma unroll
        for (int i = 0; i < 8; ++i) {
            const int v4  = i * 64 + lane;
            const int row = v4 >> 3;
            const int g   = v4 & 7;
            const float4 o = *(const float4*)&sl[row * 36 + ((g + row) & 7) * 4];
            *(float4*)(out + hbase + (long)(rbase + row) * DIM + h * 32 + g * 4) = o;
        }
        __builtin_amdgcn_wave_barrier();
    }
}

extern "C" void kernel_launch(void* const* d_in, const int* in_sizes, int n_in,
                              void* d_out, int out_size, void* d_ws, size_t ws_size,
                              hipStream_t stream) {
    const float* Q    = (const float*)d_in[0];
    const float* K    = (const float*)d_in[1];
    const float* V    = (const float*)d_in[2];
    const float* mask = (const float*)d_in[3];
    float* out = (float*)d_out;

    // 16 partials/head needs ~18.1 MB workspace; fall back to the proven 8-partial layout
    const size_t need16 = ((size_t)NHEAD * 16 * PHEAD + (size_t)NHEAD * PHEAD) * sizeof(float);
    const int sh = (ws_size >= need16) ? 4 : 3;
    const int nchunk = 1 << sh;

    float* partials = (float*)d_ws;
    float* kvf = partials + (size_t)NHEAD * nchunk * PHEAD;

    pass1_kv<<<NHEAD * nchunk, 256, 0, stream>>>(K, V, mask, partials, sh);
    reduce_kv<<<NHEAD * 8, 256, 0, stream>>>(partials, kvf, nchunk);
    pass2_out<<<NHEAD * 16, 256, 0, stream>>>(Q, kvf, out);
}